// Round 1
// baseline (140.815 us; speedup 1.0000x reference)
//
#include <hip/hip_runtime.h>
#include <hip/hip_fp16.h>

#define DIN 256
#define DOUT 128
#define KNBR 32
#define TN 40   // nodes per block in the FC kernel (50000 % 40 == 0)

// Kernel 1: h[n][o] = relu(sum_k feats[n][k] * W[o][k] + b[o]), stored as fp16.
// 256 threads: thread t handles columns c2=(t&63)*2, c2+1 for nodes ng*10..ng*10+9.
__global__ __launch_bounds__(256) void fc_relu_kernel(
    const float* __restrict__ feats, const float* __restrict__ W,
    const float* __restrict__ bias, __half* __restrict__ h, int N)
{
    __shared__ float fs[TN * DIN];   // 40 KB
    const int nb = blockIdx.x * TN;

    // Stage the 40x256 feats tile (2560 float4, 10 per thread), coalesced.
    {
        const float4* src = (const float4*)(feats + (size_t)nb * DIN);
        float4* dst = (float4*)fs;
        #pragma unroll
        for (int i = 0; i < (TN * DIN / 4) / 256; ++i)
            dst[threadIdx.x + i * 256] = src[threadIdx.x + i * 256];
    }
    __syncthreads();

    const int c2 = (threadIdx.x & 63) * 2;   // column pair
    const int ng = threadIdx.x >> 6;         // node group 0..3
    const float4* Wa  = (const float4*)(W + (size_t)c2 * DIN);
    const float4* Wb  = (const float4*)(W + (size_t)(c2 + 1) * DIN);
    const float4* fs4 = (const float4*)fs;

    float acc0[10], acc1[10];
    #pragma unroll
    for (int i = 0; i < 10; ++i) { acc0[i] = 0.f; acc1[i] = 0.f; }

    #pragma unroll 4
    for (int k4 = 0; k4 < DIN / 4; ++k4) {
        const float4 w0 = Wa[k4];
        const float4 w1 = Wb[k4];
        #pragma unroll
        for (int i = 0; i < 10; ++i) {
            // All 64 lanes of a wave read the same LDS address -> broadcast, conflict-free.
            const float4 f = fs4[(ng * 10 + i) * (DIN / 4) + k4];
            acc0[i] += f.x * w0.x + f.y * w0.y + f.z * w0.z + f.w * w0.w;
            acc1[i] += f.x * w1.x + f.y * w1.y + f.z * w1.z + f.w * w1.w;
        }
    }

    const float b0 = bias[c2];
    const float b1 = bias[c2 + 1];
    __half2* h2 = (__half2*)h;   // row stride = DOUT/2 = 64 half2
    #pragma unroll
    for (int i = 0; i < 10; ++i) {
        const int n = nb + ng * 10 + i;
        const float v0 = fmaxf(acc0[i] + b0, 0.f);
        const float v1 = fmaxf(acc1[i] + b1, 0.f);
        h2[(size_t)n * (DOUT / 2) + (threadIdx.x & 63)] = __floats2half2_rn(v0, v1);
    }
}

// Kernel 2: pooled[n][:] = mean_k h[edge[n][k]][:]
// 8 nodes per 256-thread block; 32 lanes per node, each owning 4 columns (8 B half4).
struct Half4 { __half2 a, b; };

__global__ __launch_bounds__(256) void pool_kernel(
    const __half* __restrict__ h, const int* __restrict__ edge,
    float* __restrict__ out, int N)
{
    const int lane = threadIdx.x & 31;
    const int node_local = threadIdx.x >> 5;   // 0..7
    const int n = blockIdx.x * 8 + node_local;
    if (n >= N) return;

    const Half4* h4 = (const Half4*)h;         // row stride = DOUT/4 = 32 Half4
    const int* e = edge + (size_t)n * KNBR;

    float4 acc = {0.f, 0.f, 0.f, 0.f};
    #pragma unroll
    for (int k = 0; k < KNBR; ++k) {
        const int idx = e[k];                  // same addr across the 32-lane group -> broadcast
        const Half4 v = h4[(size_t)idx * (DOUT / 4) + lane];
        const float2 fa = __half22float2(v.a);
        const float2 fb = __half22float2(v.b);
        acc.x += fa.x; acc.y += fa.y; acc.z += fb.x; acc.w += fb.y;
    }
    const float s = 1.0f / (float)KNBR;
    float4 r;
    r.x = acc.x * s; r.y = acc.y * s; r.z = acc.z * s; r.w = acc.w * s;
    ((float4*)out)[(size_t)n * (DOUT / 4) + lane] = r;
}

extern "C" void kernel_launch(void* const* d_in, const int* in_sizes, int n_in,
                              void* d_out, int out_size, void* d_ws, size_t ws_size,
                              hipStream_t stream) {
    // dict order: ids, feats, W, b, edge_dict, G, ite
    const float* feats = (const float*)d_in[1];
    const float* W     = (const float*)d_in[2];
    const float* bias  = (const float*)d_in[3];
    const int*   edge  = (const int*)d_in[4];
    float* out = (float*)d_out;

    const int N = in_sizes[1] / DIN;           // 50000
    __half* h = (__half*)d_ws;                 // N * DOUT * 2 = 12.8 MB scratch

    fc_relu_kernel<<<N / TN, 256, 0, stream>>>(feats, W, bias, h, N);
    pool_kernel<<<(N + 7) / 8, 256, 0, stream>>>(h, edge, out, N);
}

// Round 2
// 82.834 us; speedup vs baseline: 1.7000x; 1.7000x over previous
//
#include <hip/hip_runtime.h>
#include <hip/hip_fp16.h>

#define DIN 256
#define DOUT 128
#define KNBR 32
#define MT 128   // M-tile per block in FC kernel

typedef __attribute__((ext_vector_type(4))) float f32x4;
typedef __attribute__((ext_vector_type(8))) short bf16x8;

static __device__ __forceinline__ ushort f2bf(float f) {
    uint u = __float_as_uint(f);
    return (ushort)((u + 0x7FFFu + ((u >> 16) & 1u)) >> 16);   // RNE
}

// One-time W fp32 -> bf16 (32768 elems, 32 blocks x 256 thr x 4 elems)
__global__ __launch_bounds__(256) void wconv_kernel(
    const float* __restrict__ W, ushort* __restrict__ Wbf)
{
    const int idx = (blockIdx.x * 256 + threadIdx.x) * 4;
    const float4 v = *(const float4*)(W + idx);
    ushort4 o;
    o.x = f2bf(v.x); o.y = f2bf(v.y); o.z = f2bf(v.z); o.w = f2bf(v.w);
    *(ushort4*)(Wbf + idx) = o;
}

// h[n][o] = relu(feats[n][:] . W[o][:] + b[o]) via bf16 MFMA, h stored fp16.
// Block: 256 thr = 4 waves in 2x2; wave tile 64(M) x 64(N); 4x4 16x16 frags.
__global__ __launch_bounds__(256) void fc_mfma_kernel(
    const float* __restrict__ feats, const ushort* __restrict__ Wbf,
    const float* __restrict__ bias, __half* __restrict__ h, int N)
{
    __shared__ ushort lds_a[MT * DIN];   // 64 KB, XOR-swizzled bf16 A tile
    char* lds = (char*)lds_a;

    const int tid = threadIdx.x;
    const int lane = tid & 63;
    const int wv  = tid >> 6;
    const int wm  = wv >> 1, wn = wv & 1;
    const int l15 = lane & 15, lq = lane >> 4;
    const int nb  = blockIdx.x * MT;

    // ---- preload all B fragments into registers (W is L2-resident 64 KB) ----
    // b[ni][ks]: lane holds W[col = wn*64+ni*16+l15][k = ks*32 + lq*8 .. +7]
    bf16x8 breg[4][8];
    #pragma unroll
    for (int ni = 0; ni < 4; ++ni) {
        const ushort* wrow = Wbf + (size_t)(wn * 64 + ni * 16 + l15) * DIN + lq * 8;
        #pragma unroll
        for (int ks = 0; ks < 8; ++ks)
            breg[ni][ks] = *(const bf16x8*)(wrow + ks * 32);
    }

    // ---- stage A tile: fp32 global (coalesced) -> bf16 LDS (swizzled) ----
    // 128 rows x 64 float4; iter i: 256 consecutive float4 (one row per 64 thr)
    #pragma unroll
    for (int it = 0; it < 32; ++it) {
        const int idx = it * 256 + tid;
        const int row = idx >> 6;
        const int c4  = idx & 63;
        const int gr  = nb + row;
        float4 v = {0.f, 0.f, 0.f, 0.f};
        if (gr < N) v = *(const float4*)(feats + (size_t)gr * DIN + c4 * 4);
        ushort4 o;
        o.x = f2bf(v.x); o.y = f2bf(v.y); o.z = f2bf(v.z); o.w = f2bf(v.w);
        int off = row * 512 + c4 * 8;
        off ^= (row & 7) << 4;            // bank-conflict swizzle (G4)
        *(ushort4*)(lds + off) = o;
    }
    __syncthreads();

    // ---- K loop: pure ds_read + MFMA ----
    const f32x4 zero = {0.f, 0.f, 0.f, 0.f};
    f32x4 acc[4][4];
    #pragma unroll
    for (int mi = 0; mi < 4; ++mi)
        #pragma unroll
        for (int ni = 0; ni < 4; ++ni) acc[mi][ni] = zero;

    #pragma unroll
    for (int ks = 0; ks < 8; ++ks) {
        bf16x8 a[4];
        #pragma unroll
        for (int mi = 0; mi < 4; ++mi) {
            const int row = wm * 64 + mi * 16 + l15;
            int off = row * 512 + ks * 64 + lq * 16;
            off ^= (row & 7) << 4;
            a[mi] = *(const bf16x8*)(lds + off);
        }
        #pragma unroll
        for (int mi = 0; mi < 4; ++mi)
            #pragma unroll
            for (int ni = 0; ni < 4; ++ni)
                acc[mi][ni] = __builtin_amdgcn_mfma_f32_16x16x32_bf16(
                    a[mi], breg[ni][ks], acc[mi][ni], 0, 0, 0);
    }

    // ---- epilogue: bias + relu -> fp16 h ----
    // D layout: col = lane&15, row = (lane>>4)*4 + r
    float bcol[4];
    #pragma unroll
    for (int ni = 0; ni < 4; ++ni) bcol[ni] = bias[wn * 64 + ni * 16 + l15];

    #pragma unroll
    for (int mi = 0; mi < 4; ++mi) {
        const int rbase = nb + wm * 64 + mi * 16 + lq * 4;
        #pragma unroll
        for (int ni = 0; ni < 4; ++ni) {
            const int col = wn * 64 + ni * 16 + l15;
            #pragma unroll
            for (int r = 0; r < 4; ++r) {
                const int n = rbase + r;
                if (n < N) {
                    const float v = fmaxf(acc[mi][ni][r] + bcol[ni], 0.f);
                    h[(size_t)n * DOUT + col] = __float2half_rn(v);
                }
            }
        }
    }
}

// pooled[n][:] = mean_k h[edge[n][k]][:]
struct Half4 { __half2 a, b; };

__global__ __launch_bounds__(256) void pool_kernel(
    const __half* __restrict__ h, const int* __restrict__ edge,
    float* __restrict__ out, int N)
{
    const int lane = threadIdx.x & 31;
    const int node_local = threadIdx.x >> 5;
    const int n = blockIdx.x * 8 + node_local;
    if (n >= N) return;

    const Half4* h4 = (const Half4*)h;          // row stride = DOUT/4 = 32
    const int* e = edge + (size_t)n * KNBR;

    float4 acc = {0.f, 0.f, 0.f, 0.f};
    #pragma unroll
    for (int k = 0; k < KNBR; ++k) {
        const int idx = e[k];
        const Half4 v = h4[(size_t)idx * (DOUT / 4) + lane];
        const float2 fa = __half22float2(v.a);
        const float2 fb = __half22float2(v.b);
        acc.x += fa.x; acc.y += fa.y; acc.z += fb.x; acc.w += fb.y;
    }
    const float s = 1.0f / (float)KNBR;
    float4 r;
    r.x = acc.x * s; r.y = acc.y * s; r.z = acc.z * s; r.w = acc.w * s;
    ((float4*)out)[(size_t)n * (DOUT / 4) + lane] = r;
}

extern "C" void kernel_launch(void* const* d_in, const int* in_sizes, int n_in,
                              void* d_out, int out_size, void* d_ws, size_t ws_size,
                              hipStream_t stream) {
    // dict order: ids, feats, W, b, edge_dict, G, ite
    const float* feats = (const float*)d_in[1];
    const float* W     = (const float*)d_in[2];
    const float* bias  = (const float*)d_in[3];
    const int*   edge  = (const int*)d_in[4];
    float* out = (float*)d_out;

    const int N = in_sizes[1] / DIN;            // 50000
    __half* h   = (__half*)d_ws;                // N*DOUT*2 = 12.8 MB
    ushort* Wbf = (ushort*)((char*)d_ws + (size_t)N * DOUT * sizeof(__half));

    wconv_kernel<<<(DOUT * DIN) / 1024, 256, 0, stream>>>(W, Wbf);
    fc_mfma_kernel<<<(N + MT - 1) / MT, 256, 0, stream>>>(feats, Wbf, bias, h, N);
    pool_kernel<<<(N + 7) / 8, 256, 0, stream>>>(h, edge, out, N);
}